// Round 12
// baseline (327.096 us; speedup 1.0000x reference)
//
#include <hip/hip_runtime.h>

#define NN 100000   // nodes
#define NE 800000   // edges  (NE % 256 == 0)
#define NG 256      // graphs
#define CH 96       // in/hidden channels
#define OC 16       // out channels
#define NBLK 391    // ceil(NN/256)
#define TM 128      // gemm node tile (8 row-tiles of 16)
#define GBLK 782    // ceil(NN/TM)

typedef __attribute__((ext_vector_type(8))) short bf16x8;
typedef __attribute__((ext_vector_type(4))) float f32x4;

// ---------------- bf16 helpers ----------------
__device__ __forceinline__ unsigned short f2bf(float x) {
    unsigned u = __float_as_uint(x);
    return (unsigned short)((u + 0x7fffu + ((u >> 16) & 1u)) >> 16);  // RNE
}
__device__ __forceinline__ float bf2f(unsigned short h) {
    return __uint_as_float(((unsigned)h) << 16);
}
__device__ __forceinline__ void split8(const float4 a, const float4 b,
                                       bf16x8& hi, bf16x8& lo) {
    float v[8] = {a.x, a.y, a.z, a.w, b.x, b.y, b.z, b.w};
#pragma unroll
    for (int j = 0; j < 8; j++) {
        unsigned short h = f2bf(v[j]);
        hi[j] = (short)h;
        lo[j] = (short)f2bf(v[j] - bf2f(h));
    }
}
__device__ __forceinline__ float4 us4_to_f4(ushort4 u) {
    return make_float4(bf2f(u.x), bf2f(u.y), bf2f(u.z), bf2f(u.w));
}
// 4 packed bf16 pairs (uint4) -> 8 floats
__device__ __forceinline__ void unpack8(uint4 v, float* f) {
    f[0] = __uint_as_float(v.x << 16); f[1] = __uint_as_float(v.x & 0xffff0000u);
    f[2] = __uint_as_float(v.y << 16); f[3] = __uint_as_float(v.y & 0xffff0000u);
    f[4] = __uint_as_float(v.z << 16); f[5] = __uint_as_float(v.z & 0xffff0000u);
    f[6] = __uint_as_float(v.w << 16); f[7] = __uint_as_float(v.w & 0xffff0000u);
}

// ---------------- init: zero cnt/gtot + prep all 3 W -> transposed bf16 hi/lo ----
__global__ __launch_bounds__(256) void k_init(int* __restrict__ cnt,
                                              const float* __restrict__ W1,
                                              const float* __restrict__ W2,
                                              const float* __restrict__ W3,
                                              unsigned short* __restrict__ WH,
                                              unsigned short* __restrict__ WL) {
    int id = blockIdx.x * 256 + threadIdx.x;
    if (id < NN + 4) cnt[id] = 0;  // cnt + gtot slot
    if (id < 3 * CH * CH) {
        int w = id / (CH * CH);
        int r = id - w * (CH * CH);
        int k = r / CH;
        int n = r - k * CH;
        const float* Ws = (w == 0) ? W1 : (w == 1) ? W2 : W3;
        float v = Ws[k * CH + n];
        unsigned short h = f2bf(v);
        WH[w * CH * CH + n * CH + k] = h;
        WL[w * CH * CH + n * CH + k] = f2bf(v - bf2f(h));
    }
}

// ---------------- front: gemm-1 (blocks < GBLK) + edge histogram (rest) --------
// No LDS anywhere: hist blocks carry no phantom LDS reservation; W fragments
// read straight from global (36 KB, L1/L2-hot).
__global__ __launch_bounds__(256) void k_front(const float* __restrict__ X,
                                               const unsigned short* __restrict__ WH,
                                               const unsigned short* __restrict__ WL,
                                               unsigned short* __restrict__ H,
                                               const int* __restrict__ dst,
                                               int* __restrict__ cnt,
                                               int* __restrict__ slot) {
    const int tid = threadIdx.x;

    if (blockIdx.x >= GBLK) {  // ---- histogram path ----
        int e = (blockIdx.x - GBLK) * 256 + tid;
        slot[e] = atomicAdd(&cnt[dst[e]], 1);
        return;
    }

    // ---- gemm-1: H = X(fp32) @ W1, split-bf16 (3 MFMAs) ----
    const int n0 = blockIdx.x * TM;
    const int lane = tid & 63;
    const int wave = tid >> 6;
    const int lrow = lane & 15;
    const int quad = lane >> 4;

    const float4* X4 = reinterpret_cast<const float4*>(X);

    f32x4 acc[2][6];
#pragma unroll
    for (int rt = 0; rt < 2; rt++)
#pragma unroll
        for (int ct = 0; ct < 6; ct++) acc[rt][ct] = (f32x4){0.f, 0.f, 0.f, 0.f};

    int arow[2];
#pragma unroll
    for (int rt = 0; rt < 2; rt++)
        arow[rt] = min(n0 + (wave * 2 + rt) * 16 + lrow, NN - 1);

#pragma unroll
    for (int kc = 0; kc < 3; kc++) {
        bf16x8 ahi[2], alo[2];
#pragma unroll
        for (int rt = 0; rt < 2; rt++) {
            int fo = (arow[rt] * CH + kc * 32 + quad * 8) >> 2;
            split8(X4[fo], X4[fo + 1], ahi[rt], alo[rt]);
        }
#pragma unroll
        for (int ct = 0; ct < 6; ct++) {
            int bo = (ct * 16 + lrow) * CH + kc * 32 + quad * 8;
            bf16x8 bhi = *reinterpret_cast<const bf16x8*>(&WH[bo]);
            bf16x8 blo = *reinterpret_cast<const bf16x8*>(&WL[bo]);
#pragma unroll
            for (int rt = 0; rt < 2; rt++) {
                acc[rt][ct] = __builtin_amdgcn_mfma_f32_16x16x32_bf16(
                    alo[rt], bhi, acc[rt][ct], 0, 0, 0);
                acc[rt][ct] = __builtin_amdgcn_mfma_f32_16x16x32_bf16(
                    ahi[rt], blo, acc[rt][ct], 0, 0, 0);
                acc[rt][ct] = __builtin_amdgcn_mfma_f32_16x16x32_bf16(
                    ahi[rt], bhi, acc[rt][ct], 0, 0, 0);
            }
        }
    }

#pragma unroll
    for (int rt = 0; rt < 2; rt++) {
        int rbase = n0 + (wave * 2 + rt) * 16 + quad * 4;
#pragma unroll
        for (int ct = 0; ct < 6; ct++) {
            int col = ct * 16 + lrow;
#pragma unroll
            for (int r = 0; r < 4; r++) {
                int row = rbase + r;
                if (row < NN) H[(size_t)row * CH + col] = f2bf(acc[rt][ct][r]);
            }
        }
    }
}

// unordered CSR offsets via atomic bump + dinv + graph boundaries
__global__ __launch_bounds__(256) void k_offsets(const int* __restrict__ cnt,
                                                 int* __restrict__ gtot,
                                                 int* __restrict__ off,
                                                 float* __restrict__ dinv,
                                                 const int* __restrict__ batch,
                                                 int* __restrict__ goff) {
    int i = blockIdx.x * 256 + threadIdx.x;
    if (i >= NN) return;
    int c = cnt[i];
    off[i] = atomicAdd(gtot, c);
    dinv[i] = rsqrtf((float)c + 1.0f);
    int b = batch[i];
    int bp = (i > 0) ? batch[i - 1] : -1;
    for (int g = bp + 1; g <= b; g++) goff[g] = i;
    if (i == NN - 1)
        for (int g = b + 1; g <= NG; g++) goff[g] = NN;
}

__global__ __launch_bounds__(256) void k_build(const int* __restrict__ src,
                                               const int* __restrict__ dst,
                                               const int* __restrict__ off,
                                               const int* __restrict__ slot,
                                               const float* __restrict__ dinv,
                                               float2* __restrict__ packed) {
    int e = blockIdx.x * 256 + threadIdx.x;
    int s = src[e];
    int d = dst[e];
    packed[off[d] + slot[e]] = make_float2(__int_as_float(s), dinv[s] * dinv[d]);
}

// ---------------- MFMA GEMM (layers 2,3): H(bf16) = X(bf16) @ W, no LDS ----------
__global__ __launch_bounds__(256) void k_gemm_bf16(const unsigned short* __restrict__ X,
                                                   const unsigned short* __restrict__ WH,
                                                   const unsigned short* __restrict__ WL,
                                                   unsigned short* __restrict__ H) {
    const int tid = threadIdx.x;
    const int n0 = blockIdx.x * TM;
    const int lane = tid & 63;
    const int wave = tid >> 6;
    const int lrow = lane & 15;
    const int quad = lane >> 4;

    f32x4 acc[2][6];
#pragma unroll
    for (int rt = 0; rt < 2; rt++)
#pragma unroll
        for (int ct = 0; ct < 6; ct++) acc[rt][ct] = (f32x4){0.f, 0.f, 0.f, 0.f};

    int arow[2];
#pragma unroll
    for (int rt = 0; rt < 2; rt++)
        arow[rt] = min(n0 + (wave * 2 + rt) * 16 + lrow, NN - 1);

#pragma unroll
    for (int kc = 0; kc < 3; kc++) {
        bf16x8 ahi[2];
#pragma unroll
        for (int rt = 0; rt < 2; rt++)
            ahi[rt] = *reinterpret_cast<const bf16x8*>(
                &X[(size_t)arow[rt] * CH + kc * 32 + quad * 8]);
#pragma unroll
        for (int ct = 0; ct < 6; ct++) {
            int bo = (ct * 16 + lrow) * CH + kc * 32 + quad * 8;
            bf16x8 bhi = *reinterpret_cast<const bf16x8*>(&WH[bo]);
            bf16x8 blo = *reinterpret_cast<const bf16x8*>(&WL[bo]);
#pragma unroll
            for (int rt = 0; rt < 2; rt++) {
                acc[rt][ct] = __builtin_amdgcn_mfma_f32_16x16x32_bf16(
                    ahi[rt], blo, acc[rt][ct], 0, 0, 0);
                acc[rt][ct] = __builtin_amdgcn_mfma_f32_16x16x32_bf16(
                    ahi[rt], bhi, acc[rt][ct], 0, 0, 0);
            }
        }
    }

#pragma unroll
    for (int rt = 0; rt < 2; rt++) {
        int rbase = n0 + (wave * 2 + rt) * 16 + quad * 4;
#pragma unroll
        for (int ct = 0; ct < 6; ct++) {
            int col = ct * 16 + lrow;
#pragma unroll
            for (int r = 0; r < 4; r++) {
                int row = rbase + r;
                if (row < NN) H[(size_t)row * CH + col] = f2bf(acc[rt][ct][r]);
            }
        }
    }
}

// ---------------- per-dst aggregation: 12 threads/node, 8-deep 16 B gathers ------
template <bool RELU>
__global__ __launch_bounds__(256) void k_aggregate(const int* __restrict__ off,
                                                   const int* __restrict__ cnt,
                                                   const float2* __restrict__ packed,
                                                   const float* __restrict__ dinv,
                                                   const float* __restrict__ bias,
                                                   const unsigned short* __restrict__ H,
                                                   unsigned short* __restrict__ Bout) {
    int idx = blockIdx.x * 256 + threadIdx.x;  // NN*12
    if (idx >= NN * 12) return;
    int n = idx / 12;
    int c8 = idx - n * 12;  // 8 channels per thread
    int e0 = off[n];
    int e1 = e0 + cnt[n];

    const uint4* H8 = reinterpret_cast<const uint4*>(H);

    float a[8];
    {
        float hf[8];
        unpack8(H8[(size_t)n * 12 + c8], hf);
        float di = dinv[n];
        float d2 = di * di;
        const float4* bias4 = reinterpret_cast<const float4*>(bias);
        float4 b0 = bias4[c8 * 2], b1 = bias4[c8 * 2 + 1];
        float bf[8] = {b0.x, b0.y, b0.z, b0.w, b1.x, b1.y, b1.z, b1.w};
#pragma unroll
        for (int j = 0; j < 8; j++) a[j] = hf[j] * d2 + bf[j];
    }

    int e = e0;
    for (; e + 8 <= e1; e += 8) {  // 8 outstanding 16B gathers
        float2 p[8];
        uint4 v[8];
#pragma unroll
        for (int q = 0; q < 8; q++) p[q] = packed[e + q];
#pragma unroll
        for (int q = 0; q < 8; q++) v[q] = H8[(size_t)__float_as_int(p[q].x) * 12 + c8];
#pragma unroll
        for (int q = 0; q < 8; q++) {
            float f[8];
            unpack8(v[q], f);
#pragma unroll
            for (int j = 0; j < 8; j++) a[j] += f[j] * p[q].y;
        }
    }
    for (; e + 4 <= e1; e += 4) {
        float2 p[4];
        uint4 v[4];
#pragma unroll
        for (int q = 0; q < 4; q++) p[q] = packed[e + q];
#pragma unroll
        for (int q = 0; q < 4; q++) v[q] = H8[(size_t)__float_as_int(p[q].x) * 12 + c8];
#pragma unroll
        for (int q = 0; q < 4; q++) {
            float f[8];
            unpack8(v[q], f);
#pragma unroll
            for (int j = 0; j < 8; j++) a[j] += f[j] * p[q].y;
        }
    }
    for (; e < e1; e++) {
        float2 pc = packed[e];
        uint4 v = H8[(size_t)__float_as_int(pc.x) * 12 + c8];
        float f[8];
        unpack8(v, f);
#pragma unroll
        for (int j = 0; j < 8; j++) a[j] += f[j] * pc.y;
    }
    if (RELU) {
#pragma unroll
        for (int j = 0; j < 8; j++) a[j] = fmaxf(a[j], 0.0f);
    }
    uint4 o;
    o.x = (unsigned)f2bf(a[0]) | ((unsigned)f2bf(a[1]) << 16);
    o.y = (unsigned)f2bf(a[2]) | ((unsigned)f2bf(a[3]) << 16);
    o.z = (unsigned)f2bf(a[4]) | ((unsigned)f2bf(a[5]) << 16);
    o.w = (unsigned)f2bf(a[6]) | ((unsigned)f2bf(a[7]) << 16);
    reinterpret_cast<uint4*>(Bout)[(size_t)n * 12 + c8] = o;
}

// ---------------- fused pool + final linear (bf16 input) ----------------
__global__ __launch_bounds__(384) void k_pool_linear(const int* __restrict__ goff,
                                                     const unsigned short* __restrict__ B,
                                                     const float* __restrict__ Wlin,
                                                     float* __restrict__ out) {
    __shared__ float4 sh[16][24];
    __shared__ float pooled[CH];
    int g = blockIdx.x;
    int t = threadIdx.x;
    int nl = t / 24;
    int c4 = t - nl * 24;
    int s = goff[g];
    int e = goff[g + 1];

    float4 acc = make_float4(0.f, 0.f, 0.f, 0.f);
    const ushort4* B4 = reinterpret_cast<const ushort4*>(B);
    for (int n = s + nl; n < e; n += 16) {
        float4 v = us4_to_f4(B4[(size_t)n * 24 + c4]);
        acc.x += v.x; acc.y += v.y; acc.z += v.z; acc.w += v.w;
    }
    sh[nl][c4] = acc;
    __syncthreads();

    if (t < 24) {
        float4 r = make_float4(0.f, 0.f, 0.f, 0.f);
#pragma unroll
        for (int j = 0; j < 16; j++) {
            float4 v = sh[j][t];
            r.x += v.x; r.y += v.y; r.z += v.z; r.w += v.w;
        }
        float inv = 1.0f / fmaxf((float)(e - s), 1.0f);
        pooled[t * 4 + 0] = r.x * inv;
        pooled[t * 4 + 1] = r.y * inv;
        pooled[t * 4 + 2] = r.z * inv;
        pooled[t * 4 + 3] = r.w * inv;
    }
    __syncthreads();

    if (t < OC) {
        float a = 0.0f;
#pragma unroll 8
        for (int k = 0; k < CH; k++) a += pooled[k] * Wlin[k * OC + t];
        out[g * OC + t] = a;
    }
}

// ---------------- launch ----------------
extern "C" void kernel_launch(void* const* d_in, const int* in_sizes, int n_in,
                              void* d_out, int out_size, void* d_ws, size_t ws_size,
                              hipStream_t stream) {
    const float* x = (const float*)d_in[0];
    const int* ei = (const int*)d_in[1];
    const int* src = ei;
    const int* dst = ei + NE;
    const int* batch = (const int*)d_in[2];
    const float* W1 = (const float*)d_in[3];
    const float* b1 = (const float*)d_in[4];
    const float* W2 = (const float*)d_in[5];
    const float* b2 = (const float*)d_in[6];
    const float* W3 = (const float*)d_in[7];
    const float* b3 = (const float*)d_in[8];
    const float* Wlin = (const float*)d_in[9];
    float* out = (float*)d_out;

    char* ws = (char*)d_ws;
    unsigned short* Ha = (unsigned short*)ws;  ws += (size_t)NN * CH * 2;  // 19.2 MB
    unsigned short* Hb = (unsigned short*)ws;  ws += (size_t)NN * CH * 2;  // 19.2 MB
    unsigned short* Bb = (unsigned short*)ws;  ws += (size_t)NN * CH * 2;  // 19.2 MB
    float2* packed = (float2*)ws;   ws += (size_t)NE * 8;        // 6.4 MB
    unsigned short* WH = (unsigned short*)ws;  ws += 3 * CH * CH * 2;  // 55 KB
    unsigned short* WL = (unsigned short*)ws;  ws += 3 * CH * CH * 2;
    float* dinv = (float*)ws;       ws += NN * 4;
    int* off = (int*)ws;            ws += NN * 4;
    int* goff = (int*)ws;           ws += 272 * 4;       // NG+1, padded
    int* cnt = (int*)ws;            ws += (NN + 4) * 4;  // +gtot slot
    int* gtot = cnt + NN;
    int* slot = (int*)Bb;  // Bb dead until agg1 writes it; slot last read by k_build

    // init (zero cnt/gtot + W prep), front (gemm1 || hist), offsets, build
    k_init<<<NBLK, 256, 0, stream>>>(cnt, W1, W2, W3, WH, WL);
    k_front<<<GBLK + NE / 256, 256, 0, stream>>>(x, WH, WL, Ha, dst, cnt, slot);
    k_offsets<<<NBLK, 256, 0, stream>>>(cnt, gtot, off, dinv, batch, goff);
    k_build<<<NE / 256, 256, 0, stream>>>(src, dst, off, slot, dinv, packed);

    const int ablk = (NN * 12 + 255) / 256;

    // layer 1 aggregate: Ha -> Bb (relu)
    k_aggregate<true><<<ablk, 256, 0, stream>>>(off, cnt, packed, dinv, b1, Ha, Bb);
    // layer 2: Bb -> Hb -> Bb (relu)
    k_gemm_bf16<<<GBLK, 256, 0, stream>>>(Bb, WH + CH * CH, WL + CH * CH, Hb);
    k_aggregate<true><<<ablk, 256, 0, stream>>>(off, cnt, packed, dinv, b2, Hb, Bb);
    // layer 3: Bb -> Ha -> Bb (no relu)
    k_gemm_bf16<<<GBLK, 256, 0, stream>>>(Bb, WH + 2 * CH * CH, WL + 2 * CH * CH, Ha);
    k_aggregate<false><<<ablk, 256, 0, stream>>>(off, cnt, packed, dinv, b3, Ha, Bb);

    // fused pool + linear
    k_pool_linear<<<NG, 384, 0, stream>>>(goff, Bb, Wlin, out);
}

// Round 13
// 312.519 us; speedup vs baseline: 1.0466x; 1.0466x over previous
//
#include <hip/hip_runtime.h>

#define NN 100000   // nodes
#define NE 800000   // edges  (NE % 256 == 0)
#define NG 256      // graphs
#define CH 96       // in/hidden channels
#define OC 16       // out channels
#define NBLK 391    // ceil(NN/256)
#define TM 128      // gemm node tile (8 row-tiles of 16)
#define GBLK 782    // ceil(NN/TM)

typedef __attribute__((ext_vector_type(8))) short bf16x8;
typedef __attribute__((ext_vector_type(4))) float f32x4;

// ---------------- bf16 helpers ----------------
__device__ __forceinline__ unsigned short f2bf(float x) {
    unsigned u = __float_as_uint(x);
    return (unsigned short)((u + 0x7fffu + ((u >> 16) & 1u)) >> 16);  // RNE
}
__device__ __forceinline__ float bf2f(unsigned short h) {
    return __uint_as_float(((unsigned)h) << 16);
}
__device__ __forceinline__ void split8(const float4 a, const float4 b,
                                       bf16x8& hi, bf16x8& lo) {
    float v[8] = {a.x, a.y, a.z, a.w, b.x, b.y, b.z, b.w};
#pragma unroll
    for (int j = 0; j < 8; j++) {
        unsigned short h = f2bf(v[j]);
        hi[j] = (short)h;
        lo[j] = (short)f2bf(v[j] - bf2f(h));
    }
}
__device__ __forceinline__ float4 us4_to_f4(ushort4 u) {
    return make_float4(bf2f(u.x), bf2f(u.y), bf2f(u.z), bf2f(u.w));
}
// 4 packed bf16 pairs (uint4) -> 8 floats
__device__ __forceinline__ void unpack8(uint4 v, float* f) {
    f[0] = __uint_as_float(v.x << 16); f[1] = __uint_as_float(v.x & 0xffff0000u);
    f[2] = __uint_as_float(v.y << 16); f[3] = __uint_as_float(v.y & 0xffff0000u);
    f[4] = __uint_as_float(v.z << 16); f[5] = __uint_as_float(v.z & 0xffff0000u);
    f[6] = __uint_as_float(v.w << 16); f[7] = __uint_as_float(v.w & 0xffff0000u);
}

// ---------------- init: zero cnt/gtot + prep all 3 W -> transposed bf16 hi/lo ----
__global__ __launch_bounds__(256) void k_init(int* __restrict__ cnt,
                                              const float* __restrict__ W1,
                                              const float* __restrict__ W2,
                                              const float* __restrict__ W3,
                                              unsigned short* __restrict__ WH,
                                              unsigned short* __restrict__ WL) {
    int id = blockIdx.x * 256 + threadIdx.x;
    if (id < NN + 4) cnt[id] = 0;  // cnt + gtot slot
    if (id < 3 * CH * CH) {
        int w = id / (CH * CH);
        int r = id - w * (CH * CH);
        int k = r / CH;
        int n = r - k * CH;
        const float* Ws = (w == 0) ? W1 : (w == 1) ? W2 : W3;
        float v = Ws[k * CH + n];
        unsigned short h = f2bf(v);
        WH[w * CH * CH + n * CH + k] = h;
        WL[w * CH * CH + n * CH + k] = f2bf(v - bf2f(h));
    }
}

// ---------------- edge histogram (separate dispatch; merge was a loss, R12) ----
__global__ __launch_bounds__(256) void k_hist(const int* __restrict__ dst,
                                              int* __restrict__ cnt,
                                              int* __restrict__ slot) {
    int e = blockIdx.x * 256 + threadIdx.x;
    slot[e] = atomicAdd(&cnt[dst[e]], 1);
}

// ---------------- MFMA GEMM (layer 1): H(bf16) = X(fp32) @ W, LDS-staged W ------
__global__ __launch_bounds__(256) void k_gemm_f32(const float* __restrict__ X,
                                                  const unsigned short* __restrict__ WH,
                                                  const unsigned short* __restrict__ WL,
                                                  unsigned short* __restrict__ H) {
    __shared__ __align__(16) unsigned short WsH[CH * CH];  // 18 KB
    __shared__ __align__(16) unsigned short WsL[CH * CH];  // 18 KB

    const int tid = threadIdx.x;
    const int n0 = blockIdx.x * TM;

    {
        const uint4* sH = reinterpret_cast<const uint4*>(WH);
        const uint4* sL = reinterpret_cast<const uint4*>(WL);
        uint4* dH = reinterpret_cast<uint4*>(WsH);
        uint4* dL = reinterpret_cast<uint4*>(WsL);
        for (int i = tid; i < CH * CH / 8; i += 256) {
            dH[i] = sH[i];
            dL[i] = sL[i];
        }
    }
    __syncthreads();

    const int lane = tid & 63;
    const int wave = tid >> 6;
    const int lrow = lane & 15;
    const int quad = lane >> 4;

    const float4* X4 = reinterpret_cast<const float4*>(X);

    f32x4 acc[2][6];
#pragma unroll
    for (int rt = 0; rt < 2; rt++)
#pragma unroll
        for (int ct = 0; ct < 6; ct++) acc[rt][ct] = (f32x4){0.f, 0.f, 0.f, 0.f};

    int arow[2];
#pragma unroll
    for (int rt = 0; rt < 2; rt++)
        arow[rt] = min(n0 + (wave * 2 + rt) * 16 + lrow, NN - 1);

#pragma unroll
    for (int kc = 0; kc < 3; kc++) {
        bf16x8 ahi[2], alo[2];
#pragma unroll
        for (int rt = 0; rt < 2; rt++) {
            int fo = (arow[rt] * CH + kc * 32 + quad * 8) >> 2;
            split8(X4[fo], X4[fo + 1], ahi[rt], alo[rt]);
        }
#pragma unroll
        for (int ct = 0; ct < 6; ct++) {
            int bo = (ct * 16 + lrow) * CH + kc * 32 + quad * 8;
            bf16x8 bhi = *reinterpret_cast<const bf16x8*>(&WsH[bo]);
            bf16x8 blo = *reinterpret_cast<const bf16x8*>(&WsL[bo]);
#pragma unroll
            for (int rt = 0; rt < 2; rt++) {
                acc[rt][ct] = __builtin_amdgcn_mfma_f32_16x16x32_bf16(
                    alo[rt], bhi, acc[rt][ct], 0, 0, 0);
                acc[rt][ct] = __builtin_amdgcn_mfma_f32_16x16x32_bf16(
                    ahi[rt], blo, acc[rt][ct], 0, 0, 0);
                acc[rt][ct] = __builtin_amdgcn_mfma_f32_16x16x32_bf16(
                    ahi[rt], bhi, acc[rt][ct], 0, 0, 0);
            }
        }
    }

#pragma unroll
    for (int rt = 0; rt < 2; rt++) {
        int rbase = n0 + (wave * 2 + rt) * 16 + quad * 4;
#pragma unroll
        for (int ct = 0; ct < 6; ct++) {
            int col = ct * 16 + lrow;
#pragma unroll
            for (int r = 0; r < 4; r++) {
                int row = rbase + r;
                if (row < NN) H[(size_t)row * CH + col] = f2bf(acc[rt][ct][r]);
            }
        }
    }
}

// unordered CSR offsets via atomic bump + dinv + graph boundaries
__global__ __launch_bounds__(256) void k_offsets(const int* __restrict__ cnt,
                                                 int* __restrict__ gtot,
                                                 int* __restrict__ off,
                                                 float* __restrict__ dinv,
                                                 const int* __restrict__ batch,
                                                 int* __restrict__ goff) {
    int i = blockIdx.x * 256 + threadIdx.x;
    if (i >= NN) return;
    int c = cnt[i];
    off[i] = atomicAdd(gtot, c);
    dinv[i] = rsqrtf((float)c + 1.0f);
    int b = batch[i];
    int bp = (i > 0) ? batch[i - 1] : -1;
    for (int g = bp + 1; g <= b; g++) goff[g] = i;
    if (i == NN - 1)
        for (int g = b + 1; g <= NG; g++) goff[g] = NN;
}

__global__ __launch_bounds__(256) void k_build(const int* __restrict__ src,
                                               const int* __restrict__ dst,
                                               const int* __restrict__ off,
                                               const int* __restrict__ slot,
                                               const float* __restrict__ dinv,
                                               float2* __restrict__ packed) {
    int e = blockIdx.x * 256 + threadIdx.x;
    int s = src[e];
    int d = dst[e];
    packed[off[d] + slot[e]] = make_float2(__int_as_float(s), dinv[s] * dinv[d]);
}

// ---------------- MFMA GEMM (layers 2,3): H(bf16) = X(bf16) @ W, LDS-staged W ---
__global__ __launch_bounds__(256) void k_gemm_bf16(const unsigned short* __restrict__ X,
                                                   const unsigned short* __restrict__ WH,
                                                   const unsigned short* __restrict__ WL,
                                                   unsigned short* __restrict__ H) {
    __shared__ __align__(16) unsigned short WsH[CH * CH];
    __shared__ __align__(16) unsigned short WsL[CH * CH];

    const int tid = threadIdx.x;
    const int n0 = blockIdx.x * TM;

    {
        const uint4* sH = reinterpret_cast<const uint4*>(WH);
        const uint4* sL = reinterpret_cast<const uint4*>(WL);
        uint4* dH = reinterpret_cast<uint4*>(WsH);
        uint4* dL = reinterpret_cast<uint4*>(WsL);
        for (int i = tid; i < CH * CH / 8; i += 256) {
            dH[i] = sH[i];
            dL[i] = sL[i];
        }
    }
    __syncthreads();

    const int lane = tid & 63;
    const int wave = tid >> 6;
    const int lrow = lane & 15;
    const int quad = lane >> 4;

    f32x4 acc[2][6];
#pragma unroll
    for (int rt = 0; rt < 2; rt++)
#pragma unroll
        for (int ct = 0; ct < 6; ct++) acc[rt][ct] = (f32x4){0.f, 0.f, 0.f, 0.f};

    int arow[2];
#pragma unroll
    for (int rt = 0; rt < 2; rt++)
        arow[rt] = min(n0 + (wave * 2 + rt) * 16 + lrow, NN - 1);

#pragma unroll
    for (int kc = 0; kc < 3; kc++) {
        bf16x8 ahi[2];
#pragma unroll
        for (int rt = 0; rt < 2; rt++)
            ahi[rt] = *reinterpret_cast<const bf16x8*>(
                &X[(size_t)arow[rt] * CH + kc * 32 + quad * 8]);
#pragma unroll
        for (int ct = 0; ct < 6; ct++) {
            int bo = (ct * 16 + lrow) * CH + kc * 32 + quad * 8;
            bf16x8 bhi = *reinterpret_cast<const bf16x8*>(&WsH[bo]);
            bf16x8 blo = *reinterpret_cast<const bf16x8*>(&WsL[bo]);
#pragma unroll
            for (int rt = 0; rt < 2; rt++) {
                acc[rt][ct] = __builtin_amdgcn_mfma_f32_16x16x32_bf16(
                    ahi[rt], blo, acc[rt][ct], 0, 0, 0);
                acc[rt][ct] = __builtin_amdgcn_mfma_f32_16x16x32_bf16(
                    ahi[rt], bhi, acc[rt][ct], 0, 0, 0);
            }
        }
    }

#pragma unroll
    for (int rt = 0; rt < 2; rt++) {
        int rbase = n0 + (wave * 2 + rt) * 16 + quad * 4;
#pragma unroll
        for (int ct = 0; ct < 6; ct++) {
            int col = ct * 16 + lrow;
#pragma unroll
            for (int r = 0; r < 4; r++) {
                int row = rbase + r;
                if (row < NN) H[(size_t)row * CH + col] = f2bf(acc[rt][ct][r]);
            }
        }
    }
}

// ---------------- per-dst aggregation: 12 threads/node, 4-deep 16 B gathers ------
template <bool RELU>
__global__ __launch_bounds__(256) void k_aggregate(const int* __restrict__ off,
                                                   const int* __restrict__ cnt,
                                                   const float2* __restrict__ packed,
                                                   const float* __restrict__ dinv,
                                                   const float* __restrict__ bias,
                                                   const unsigned short* __restrict__ H,
                                                   unsigned short* __restrict__ Bout) {
    int idx = blockIdx.x * 256 + threadIdx.x;  // NN*12
    if (idx >= NN * 12) return;
    int n = idx / 12;
    int c8 = idx - n * 12;  // 8 channels per thread
    int e0 = off[n];
    int e1 = e0 + cnt[n];

    const uint4* H8 = reinterpret_cast<const uint4*>(H);

    float a[8];
    {
        float hf[8];
        unpack8(H8[(size_t)n * 12 + c8], hf);
        float di = dinv[n];
        float d2 = di * di;
        const float4* bias4 = reinterpret_cast<const float4*>(bias);
        float4 b0 = bias4[c8 * 2], b1 = bias4[c8 * 2 + 1];
        float bf[8] = {b0.x, b0.y, b0.z, b0.w, b1.x, b1.y, b1.z, b1.w};
#pragma unroll
        for (int j = 0; j < 8; j++) a[j] = hf[j] * d2 + bf[j];
    }

    int e = e0;
    for (; e + 4 <= e1; e += 4) {  // 4 outstanding 16B gathers
        float2 p0 = packed[e + 0];
        float2 p1 = packed[e + 1];
        float2 p2 = packed[e + 2];
        float2 p3 = packed[e + 3];
        uint4 v0 = H8[(size_t)__float_as_int(p0.x) * 12 + c8];
        uint4 v1 = H8[(size_t)__float_as_int(p1.x) * 12 + c8];
        uint4 v2 = H8[(size_t)__float_as_int(p2.x) * 12 + c8];
        uint4 v3 = H8[(size_t)__float_as_int(p3.x) * 12 + c8];
        float f0[8], f1[8], f2[8], f3[8];
        unpack8(v0, f0); unpack8(v1, f1); unpack8(v2, f2); unpack8(v3, f3);
#pragma unroll
        for (int j = 0; j < 8; j++)
            a[j] += f0[j] * p0.y + f1[j] * p1.y + f2[j] * p2.y + f3[j] * p3.y;
    }
    for (; e < e1; e++) {
        float2 pc = packed[e];
        uint4 v = H8[(size_t)__float_as_int(pc.x) * 12 + c8];
        float f[8];
        unpack8(v, f);
#pragma unroll
        for (int j = 0; j < 8; j++) a[j] += f[j] * pc.y;
    }
    if (RELU) {
#pragma unroll
        for (int j = 0; j < 8; j++) a[j] = fmaxf(a[j], 0.0f);
    }
    uint4 o;
    o.x = (unsigned)f2bf(a[0]) | ((unsigned)f2bf(a[1]) << 16);
    o.y = (unsigned)f2bf(a[2]) | ((unsigned)f2bf(a[3]) << 16);
    o.z = (unsigned)f2bf(a[4]) | ((unsigned)f2bf(a[5]) << 16);
    o.w = (unsigned)f2bf(a[6]) | ((unsigned)f2bf(a[7]) << 16);
    reinterpret_cast<uint4*>(Bout)[(size_t)n * 12 + c8] = o;
}

// ---------------- fused pool + final linear (bf16 input) ----------------
__global__ __launch_bounds__(384) void k_pool_linear(const int* __restrict__ goff,
                                                     const unsigned short* __restrict__ B,
                                                     const float* __restrict__ Wlin,
                                                     float* __restrict__ out) {
    __shared__ float4 sh[16][24];
    __shared__ float pooled[CH];
    int g = blockIdx.x;
    int t = threadIdx.x;
    int nl = t / 24;
    int c4 = t - nl * 24;
    int s = goff[g];
    int e = goff[g + 1];

    float4 acc = make_float4(0.f, 0.f, 0.f, 0.f);
    const ushort4* B4 = reinterpret_cast<const ushort4*>(B);
    for (int n = s + nl; n < e; n += 16) {
        float4 v = us4_to_f4(B4[(size_t)n * 24 + c4]);
        acc.x += v.x; acc.y += v.y; acc.z += v.z; acc.w += v.w;
    }
    sh[nl][c4] = acc;
    __syncthreads();

    if (t < 24) {
        float4 r = make_float4(0.f, 0.f, 0.f, 0.f);
#pragma unroll
        for (int j = 0; j < 16; j++) {
            float4 v = sh[j][t];
            r.x += v.x; r.y += v.y; r.z += v.z; r.w += v.w;
        }
        float inv = 1.0f / fmaxf((float)(e - s), 1.0f);
        pooled[t * 4 + 0] = r.x * inv;
        pooled[t * 4 + 1] = r.y * inv;
        pooled[t * 4 + 2] = r.z * inv;
        pooled[t * 4 + 3] = r.w * inv;
    }
    __syncthreads();

    if (t < OC) {
        float a = 0.0f;
#pragma unroll 8
        for (int k = 0; k < CH; k++) a += pooled[k] * Wlin[k * OC + t];
        out[g * OC + t] = a;
    }
}

// ---------------- launch ----------------
extern "C" void kernel_launch(void* const* d_in, const int* in_sizes, int n_in,
                              void* d_out, int out_size, void* d_ws, size_t ws_size,
                              hipStream_t stream) {
    const float* x = (const float*)d_in[0];
    const int* ei = (const int*)d_in[1];
    const int* src = ei;
    const int* dst = ei + NE;
    const int* batch = (const int*)d_in[2];
    const float* W1 = (const float*)d_in[3];
    const float* b1 = (const float*)d_in[4];
    const float* W2 = (const float*)d_in[5];
    const float* b2 = (const float*)d_in[6];
    const float* W3 = (const float*)d_in[7];
    const float* b3 = (const float*)d_in[8];
    const float* Wlin = (const float*)d_in[9];
    float* out = (float*)d_out;

    char* ws = (char*)d_ws;
    unsigned short* Ha = (unsigned short*)ws;  ws += (size_t)NN * CH * 2;  // 19.2 MB
    unsigned short* Hb = (unsigned short*)ws;  ws += (size_t)NN * CH * 2;  // 19.2 MB
    unsigned short* Bb = (unsigned short*)ws;  ws += (size_t)NN * CH * 2;  // 19.2 MB
    float2* packed = (float2*)ws;   ws += (size_t)NE * 8;        // 6.4 MB
    unsigned short* WH = (unsigned short*)ws;  ws += 3 * CH * CH * 2;  // 55 KB
    unsigned short* WL = (unsigned short*)ws;  ws += 3 * CH * CH * 2;
    float* dinv = (float*)ws;       ws += NN * 4;
    int* off = (int*)ws;            ws += NN * 4;
    int* goff = (int*)ws;           ws += 272 * 4;       // NG+1, padded
    int* cnt = (int*)ws;            ws += (NN + 4) * 4;  // +gtot slot
    int* gtot = cnt + NN;
    int* slot = (int*)Bb;  // Bb dead until agg1 writes it; slot last read by k_build

    // init (zero cnt/gtot + W prep), hist, gemm1, offsets, build
    k_init<<<NBLK, 256, 0, stream>>>(cnt, W1, W2, W3, WH, WL);
    k_hist<<<NE / 256, 256, 0, stream>>>(dst, cnt, slot);
    k_gemm_f32<<<GBLK, 256, 0, stream>>>(x, WH, WL, Ha);
    k_offsets<<<NBLK, 256, 0, stream>>>(cnt, gtot, off, dinv, batch, goff);
    k_build<<<NE / 256, 256, 0, stream>>>(src, dst, off, slot, dinv, packed);

    const int ablk = (NN * 12 + 255) / 256;

    // layer 1 aggregate: Ha -> Bb (relu)
    k_aggregate<true><<<ablk, 256, 0, stream>>>(off, cnt, packed, dinv, b1, Ha, Bb);
    // layer 2: Bb -> Hb -> Bb (relu)
    k_gemm_bf16<<<GBLK, 256, 0, stream>>>(Bb, WH + CH * CH, WL + CH * CH, Hb);
    k_aggregate<true><<<ablk, 256, 0, stream>>>(off, cnt, packed, dinv, b2, Hb, Bb);
    // layer 3: Bb -> Ha -> Bb (no relu)
    k_gemm_bf16<<<GBLK, 256, 0, stream>>>(Bb, WH + 2 * CH * CH, WL + 2 * CH * CH, Ha);
    k_aggregate<false><<<ablk, 256, 0, stream>>>(off, cnt, packed, dinv, b3, Ha, Bb);

    // fused pool + linear
    k_pool_linear<<<NG, 384, 0, stream>>>(goff, Bb, Wlin, out);
}

// Round 14
// 310.081 us; speedup vs baseline: 1.0549x; 1.0079x over previous
//
#include <hip/hip_runtime.h>

#define NN 100000   // nodes
#define NE 800000   // edges  (NE % 256 == 0)
#define NG 256      // graphs
#define CH 96       // in/hidden channels
#define OC 16       // out channels
#define NBLK 391    // ceil(NN/256)
#define TM 128      // gemm node tile (8 row-tiles of 16)
#define GBLK 782    // ceil(NN/TM)

typedef __attribute__((ext_vector_type(8))) short bf16x8;
typedef __attribute__((ext_vector_type(4))) float f32x4;

// ---------------- bf16 helpers ----------------
__device__ __forceinline__ unsigned short f2bf(float x) {
    unsigned u = __float_as_uint(x);
    return (unsigned short)((u + 0x7fffu + ((u >> 16) & 1u)) >> 16);  // RNE
}
__device__ __forceinline__ float bf2f(unsigned short h) {
    return __uint_as_float(((unsigned)h) << 16);
}
__device__ __forceinline__ void split8(const float4 a, const float4 b,
                                       bf16x8& hi, bf16x8& lo) {
    float v[8] = {a.x, a.y, a.z, a.w, b.x, b.y, b.z, b.w};
#pragma unroll
    for (int j = 0; j < 8; j++) {
        unsigned short h = f2bf(v[j]);
        hi[j] = (short)h;
        lo[j] = (short)f2bf(v[j] - bf2f(h));
    }
}
__device__ __forceinline__ float4 us4_to_f4(ushort4 u) {
    return make_float4(bf2f(u.x), bf2f(u.y), bf2f(u.z), bf2f(u.w));
}
// 4 packed bf16 pairs (uint4) -> 8 floats
__device__ __forceinline__ void unpack8(uint4 v, float* f) {
    f[0] = __uint_as_float(v.x << 16); f[1] = __uint_as_float(v.x & 0xffff0000u);
    f[2] = __uint_as_float(v.y << 16); f[3] = __uint_as_float(v.y & 0xffff0000u);
    f[4] = __uint_as_float(v.z << 16); f[5] = __uint_as_float(v.z & 0xffff0000u);
    f[6] = __uint_as_float(v.w << 16); f[7] = __uint_as_float(v.w & 0xffff0000u);
}

// ---------------- init: zero cnt/gtot + prep all 3 W -> transposed bf16 hi/lo ----
__global__ __launch_bounds__(256) void k_init(int* __restrict__ cnt,
                                              const float* __restrict__ W1,
                                              const float* __restrict__ W2,
                                              const float* __restrict__ W3,
                                              unsigned short* __restrict__ WH,
                                              unsigned short* __restrict__ WL) {
    int id = blockIdx.x * 256 + threadIdx.x;
    if (id < NN + 4) cnt[id] = 0;  // cnt + gtot slot
    if (id < 3 * CH * CH) {
        int w = id / (CH * CH);
        int r = id - w * (CH * CH);
        int k = r / CH;
        int n = r - k * CH;
        const float* Ws = (w == 0) ? W1 : (w == 1) ? W2 : W3;
        float v = Ws[k * CH + n];
        unsigned short h = f2bf(v);
        WH[w * CH * CH + n * CH + k] = h;
        WL[w * CH * CH + n * CH + k] = f2bf(v - bf2f(h));
    }
}

// ---------------- front: gemm-1 (blocks < GBLK) + edge histogram (rest) --------
// R11-proven: merged dispatch, LDS-staged W. (R12's no-LDS variant regressed;
// R13's split regressed — keep this exact structure.)
__global__ __launch_bounds__(256) void k_front(const float* __restrict__ X,
                                               const unsigned short* __restrict__ WH,
                                               const unsigned short* __restrict__ WL,
                                               unsigned short* __restrict__ H,
                                               const int* __restrict__ dst,
                                               int* __restrict__ cnt,
                                               int* __restrict__ slot) {
    __shared__ __align__(16) unsigned short WsH[CH * CH];  // 18 KB
    __shared__ __align__(16) unsigned short WsL[CH * CH];  // 18 KB

    const int tid = threadIdx.x;

    if (blockIdx.x >= GBLK) {  // ---- histogram path ----
        int e = (blockIdx.x - GBLK) * 256 + tid;
        slot[e] = atomicAdd(&cnt[dst[e]], 1);
        return;
    }

    // ---- gemm-1 path: H = X(fp32) @ W1, split-bf16 (3 MFMAs) ----
    const int n0 = blockIdx.x * TM;
    {
        const uint4* sH = reinterpret_cast<const uint4*>(WH);
        const uint4* sL = reinterpret_cast<const uint4*>(WL);
        uint4* dH = reinterpret_cast<uint4*>(WsH);
        uint4* dL = reinterpret_cast<uint4*>(WsL);
        for (int i = tid; i < CH * CH / 8; i += 256) {
            dH[i] = sH[i];
            dL[i] = sL[i];
        }
    }
    __syncthreads();

    const int lane = tid & 63;
    const int wave = tid >> 6;
    const int lrow = lane & 15;
    const int quad = lane >> 4;

    const float4* X4 = reinterpret_cast<const float4*>(X);

    f32x4 acc[2][6];
#pragma unroll
    for (int rt = 0; rt < 2; rt++)
#pragma unroll
        for (int ct = 0; ct < 6; ct++) acc[rt][ct] = (f32x4){0.f, 0.f, 0.f, 0.f};

    int arow[2];
#pragma unroll
    for (int rt = 0; rt < 2; rt++)
        arow[rt] = min(n0 + (wave * 2 + rt) * 16 + lrow, NN - 1);

#pragma unroll
    for (int kc = 0; kc < 3; kc++) {
        bf16x8 ahi[2], alo[2];
#pragma unroll
        for (int rt = 0; rt < 2; rt++) {
            int fo = (arow[rt] * CH + kc * 32 + quad * 8) >> 2;
            split8(X4[fo], X4[fo + 1], ahi[rt], alo[rt]);
        }
#pragma unroll
        for (int ct = 0; ct < 6; ct++) {
            int bo = (ct * 16 + lrow) * CH + kc * 32 + quad * 8;
            bf16x8 bhi = *reinterpret_cast<const bf16x8*>(&WsH[bo]);
            bf16x8 blo = *reinterpret_cast<const bf16x8*>(&WsL[bo]);
#pragma unroll
            for (int rt = 0; rt < 2; rt++) {
                acc[rt][ct] = __builtin_amdgcn_mfma_f32_16x16x32_bf16(
                    alo[rt], bhi, acc[rt][ct], 0, 0, 0);
                acc[rt][ct] = __builtin_amdgcn_mfma_f32_16x16x32_bf16(
                    ahi[rt], blo, acc[rt][ct], 0, 0, 0);
                acc[rt][ct] = __builtin_amdgcn_mfma_f32_16x16x32_bf16(
                    ahi[rt], bhi, acc[rt][ct], 0, 0, 0);
            }
        }
    }

#pragma unroll
    for (int rt = 0; rt < 2; rt++) {
        int rbase = n0 + (wave * 2 + rt) * 16 + quad * 4;
#pragma unroll
        for (int ct = 0; ct < 6; ct++) {
            int col = ct * 16 + lrow;
#pragma unroll
            for (int r = 0; r < 4; r++) {
                int row = rbase + r;
                if (row < NN) H[(size_t)row * CH + col] = f2bf(acc[rt][ct][r]);
            }
        }
    }
}

// unordered CSR offsets via atomic bump + dinv + graph boundaries
__global__ __launch_bounds__(256) void k_offsets(const int* __restrict__ cnt,
                                                 int* __restrict__ gtot,
                                                 int* __restrict__ off,
                                                 float* __restrict__ dinv,
                                                 const int* __restrict__ batch,
                                                 int* __restrict__ goff) {
    int i = blockIdx.x * 256 + threadIdx.x;
    if (i >= NN) return;
    int c = cnt[i];
    off[i] = atomicAdd(gtot, c);
    dinv[i] = rsqrtf((float)c + 1.0f);
    int b = batch[i];
    int bp = (i > 0) ? batch[i - 1] : -1;
    for (int g = bp + 1; g <= b; g++) goff[g] = i;
    if (i == NN - 1)
        for (int g = b + 1; g <= NG; g++) goff[g] = NN;
}

__global__ __launch_bounds__(256) void k_build(const int* __restrict__ src,
                                               const int* __restrict__ dst,
                                               const int* __restrict__ off,
                                               const int* __restrict__ slot,
                                               const float* __restrict__ dinv,
                                               float2* __restrict__ packed) {
    int e = blockIdx.x * 256 + threadIdx.x;
    int s = src[e];
    int d = dst[e];
    packed[off[d] + slot[e]] = make_float2(__int_as_float(s), dinv[s] * dinv[d]);
}

// ---------------- MFMA GEMM (layers 2,3): H(bf16) = X(bf16) @ W, LDS-staged W ---
__global__ __launch_bounds__(256) void k_gemm_bf16(const unsigned short* __restrict__ X,
                                                   const unsigned short* __restrict__ WH,
                                                   const unsigned short* __restrict__ WL,
                                                   unsigned short* __restrict__ H) {
    __shared__ __align__(16) unsigned short WsH[CH * CH];
    __shared__ __align__(16) unsigned short WsL[CH * CH];

    const int tid = threadIdx.x;
    const int n0 = blockIdx.x * TM;

    {
        const uint4* sH = reinterpret_cast<const uint4*>(WH);
        const uint4* sL = reinterpret_cast<const uint4*>(WL);
        uint4* dH = reinterpret_cast<uint4*>(WsH);
        uint4* dL = reinterpret_cast<uint4*>(WsL);
        for (int i = tid; i < CH * CH / 8; i += 256) {
            dH[i] = sH[i];
            dL[i] = sL[i];
        }
    }
    __syncthreads();

    const int lane = tid & 63;
    const int wave = tid >> 6;
    const int lrow = lane & 15;
    const int quad = lane >> 4;

    f32x4 acc[2][6];
#pragma unroll
    for (int rt = 0; rt < 2; rt++)
#pragma unroll
        for (int ct = 0; ct < 6; ct++) acc[rt][ct] = (f32x4){0.f, 0.f, 0.f, 0.f};

    int arow[2];
#pragma unroll
    for (int rt = 0; rt < 2; rt++)
        arow[rt] = min(n0 + (wave * 2 + rt) * 16 + lrow, NN - 1);

#pragma unroll
    for (int kc = 0; kc < 3; kc++) {
        bf16x8 ahi[2];
#pragma unroll
        for (int rt = 0; rt < 2; rt++)
            ahi[rt] = *reinterpret_cast<const bf16x8*>(
                &X[(size_t)arow[rt] * CH + kc * 32 + quad * 8]);
#pragma unroll
        for (int ct = 0; ct < 6; ct++) {
            int bo = (ct * 16 + lrow) * CH + kc * 32 + quad * 8;
            bf16x8 bhi = *reinterpret_cast<const bf16x8*>(&WsH[bo]);
            bf16x8 blo = *reinterpret_cast<const bf16x8*>(&WsL[bo]);
#pragma unroll
            for (int rt = 0; rt < 2; rt++) {
                acc[rt][ct] = __builtin_amdgcn_mfma_f32_16x16x32_bf16(
                    ahi[rt], blo, acc[rt][ct], 0, 0, 0);
                acc[rt][ct] = __builtin_amdgcn_mfma_f32_16x16x32_bf16(
                    ahi[rt], bhi, acc[rt][ct], 0, 0, 0);
            }
        }
    }

#pragma unroll
    for (int rt = 0; rt < 2; rt++) {
        int rbase = n0 + (wave * 2 + rt) * 16 + quad * 4;
#pragma unroll
        for (int ct = 0; ct < 6; ct++) {
            int col = ct * 16 + lrow;
#pragma unroll
            for (int r = 0; r < 4; r++) {
                int row = rbase + r;
                if (row < NN) H[(size_t)row * CH + col] = f2bf(acc[rt][ct][r]);
            }
        }
    }
}

// ---------------- per-dst aggregation: 12 threads/node, 6-deep 16 B gathers ------
// Only change vs R11: pipeline depth 4 -> 6 (+2-deep tail). VGPR stays <=64.
template <bool RELU>
__global__ __launch_bounds__(256) void k_aggregate(const int* __restrict__ off,
                                                   const int* __restrict__ cnt,
                                                   const float2* __restrict__ packed,
                                                   const float* __restrict__ dinv,
                                                   const float* __restrict__ bias,
                                                   const unsigned short* __restrict__ H,
                                                   unsigned short* __restrict__ Bout) {
    int idx = blockIdx.x * 256 + threadIdx.x;  // NN*12
    if (idx >= NN * 12) return;
    int n = idx / 12;
    int c8 = idx - n * 12;  // 8 channels per thread
    int e0 = off[n];
    int e1 = e0 + cnt[n];

    const uint4* H8 = reinterpret_cast<const uint4*>(H);

    float a[8];
    {
        float hf[8];
        unpack8(H8[(size_t)n * 12 + c8], hf);
        float di = dinv[n];
        float d2 = di * di;
        const float4* bias4 = reinterpret_cast<const float4*>(bias);
        float4 b0 = bias4[c8 * 2], b1 = bias4[c8 * 2 + 1];
        float bf[8] = {b0.x, b0.y, b0.z, b0.w, b1.x, b1.y, b1.z, b1.w};
#pragma unroll
        for (int j = 0; j < 8; j++) a[j] = hf[j] * d2 + bf[j];
    }

    int e = e0;
    for (; e + 6 <= e1; e += 6) {  // 6 outstanding 16B gathers
        float2 p[6];
        uint4 v[6];
#pragma unroll
        for (int q = 0; q < 6; q++) p[q] = packed[e + q];
#pragma unroll
        for (int q = 0; q < 6; q++) v[q] = H8[(size_t)__float_as_int(p[q].x) * 12 + c8];
#pragma unroll
        for (int q = 0; q < 6; q++) {
            float f[8];
            unpack8(v[q], f);
#pragma unroll
            for (int j = 0; j < 8; j++) a[j] += f[j] * p[q].y;
        }
    }
    for (; e + 2 <= e1; e += 2) {  // 2-deep tail
        float2 p0 = packed[e + 0];
        float2 p1 = packed[e + 1];
        uint4 v0 = H8[(size_t)__float_as_int(p0.x) * 12 + c8];
        uint4 v1 = H8[(size_t)__float_as_int(p1.x) * 12 + c8];
        float f0[8], f1[8];
        unpack8(v0, f0); unpack8(v1, f1);
#pragma unroll
        for (int j = 0; j < 8; j++) a[j] += f0[j] * p0.y + f1[j] * p1.y;
    }
    if (e < e1) {
        float2 pc = packed[e];
        uint4 v = H8[(size_t)__float_as_int(pc.x) * 12 + c8];
        float f[8];
        unpack8(v, f);
#pragma unroll
        for (int j = 0; j < 8; j++) a[j] += f[j] * pc.y;
    }
    if (RELU) {
#pragma unroll
        for (int j = 0; j < 8; j++) a[j] = fmaxf(a[j], 0.0f);
    }
    uint4 o;
    o.x = (unsigned)f2bf(a[0]) | ((unsigned)f2bf(a[1]) << 16);
    o.y = (unsigned)f2bf(a[2]) | ((unsigned)f2bf(a[3]) << 16);
    o.z = (unsigned)f2bf(a[4]) | ((unsigned)f2bf(a[5]) << 16);
    o.w = (unsigned)f2bf(a[6]) | ((unsigned)f2bf(a[7]) << 16);
    reinterpret_cast<uint4*>(Bout)[(size_t)n * 12 + c8] = o;
}

// ---------------- fused pool + final linear (bf16 input) ----------------
__global__ __launch_bounds__(384) void k_pool_linear(const int* __restrict__ goff,
                                                     const unsigned short* __restrict__ B,
                                                     const float* __restrict__ Wlin,
                                                     float* __restrict__ out) {
    __shared__ float4 sh[16][24];
    __shared__ float pooled[CH];
    int g = blockIdx.x;
    int t = threadIdx.x;
    int nl = t / 24;
    int c4 = t - nl * 24;
    int s = goff[g];
    int e = goff[g + 1];

    float4 acc = make_float4(0.f, 0.f, 0.f, 0.f);
    const ushort4* B4 = reinterpret_cast<const ushort4*>(B);
    for (int n = s + nl; n < e; n += 16) {
        float4 v = us4_to_f4(B4[(size_t)n * 24 + c4]);
        acc.x += v.x; acc.y += v.y; acc.z += v.z; acc.w += v.w;
    }
    sh[nl][c4] = acc;
    __syncthreads();

    if (t < 24) {
        float4 r = make_float4(0.f, 0.f, 0.f, 0.f);
#pragma unroll
        for (int j = 0; j < 16; j++) {
            float4 v = sh[j][t];
            r.x += v.x; r.y += v.y; r.z += v.z; r.w += v.w;
        }
        float inv = 1.0f / fmaxf((float)(e - s), 1.0f);
        pooled[t * 4 + 0] = r.x * inv;
        pooled[t * 4 + 1] = r.y * inv;
        pooled[t * 4 + 2] = r.z * inv;
        pooled[t * 4 + 3] = r.w * inv;
    }
    __syncthreads();

    if (t < OC) {
        float a = 0.0f;
#pragma unroll 8
        for (int k = 0; k < CH; k++) a += pooled[k] * Wlin[k * OC + t];
        out[g * OC + t] = a;
    }
}

// ---------------- launch ----------------
extern "C" void kernel_launch(void* const* d_in, const int* in_sizes, int n_in,
                              void* d_out, int out_size, void* d_ws, size_t ws_size,
                              hipStream_t stream) {
    const float* x = (const float*)d_in[0];
    const int* ei = (const int*)d_in[1];
    const int* src = ei;
    const int* dst = ei + NE;
    const int* batch = (const int*)d_in[2];
    const float* W1 = (const float*)d_in[3];
    const float* b1 = (const float*)d_in[4];
    const float* W2 = (const float*)d_in[5];
    const float* b2 = (const float*)d_in[6];
    const float* W3 = (const float*)d_in[7];
    const float* b3 = (const float*)d_in[8];
    const float* Wlin = (const float*)d_in[9];
    float* out = (float*)d_out;

    char* ws = (char*)d_ws;
    unsigned short* Ha = (unsigned short*)ws;  ws += (size_t)NN * CH * 2;  // 19.2 MB
    unsigned short* Hb = (unsigned short*)ws;  ws += (size_t)NN * CH * 2;  // 19.2 MB
    unsigned short* Bb = (unsigned short*)ws;  ws += (size_t)NN * CH * 2;  // 19.2 MB
    float2* packed = (float2*)ws;   ws += (size_t)NE * 8;        // 6.4 MB
    unsigned short* WH = (unsigned short*)ws;  ws += 3 * CH * CH * 2;  // 55 KB
    unsigned short* WL = (unsigned short*)ws;  ws += 3 * CH * CH * 2;
    float* dinv = (float*)ws;       ws += NN * 4;
    int* off = (int*)ws;            ws += NN * 4;
    int* goff = (int*)ws;           ws += 272 * 4;       // NG+1, padded
    int* cnt = (int*)ws;            ws += (NN + 4) * 4;  // +gtot slot
    int* gtot = cnt + NN;
    int* slot = (int*)Bb;  // Bb dead until agg1 writes it; slot last read by k_build

    // init (zero cnt/gtot + W prep), front (gemm1 || hist), offsets, build
    k_init<<<NBLK, 256, 0, stream>>>(cnt, W1, W2, W3, WH, WL);
    k_front<<<GBLK + NE / 256, 256, 0, stream>>>(x, WH, WL, Ha, dst, cnt, slot);
    k_offsets<<<NBLK, 256, 0, stream>>>(cnt, gtot, off, dinv, batch, goff);
    k_build<<<NE / 256, 256, 0, stream>>>(src, dst, off, slot, dinv, packed);

    const int ablk = (NN * 12 + 255) / 256;

    // layer 1 aggregate: Ha -> Bb (relu)
    k_aggregate<true><<<ablk, 256, 0, stream>>>(off, cnt, packed, dinv, b1, Ha, Bb);
    // layer 2: Bb -> Hb -> Bb (relu)
    k_gemm_bf16<<<GBLK, 256, 0, stream>>>(Bb, WH + CH * CH, WL + CH * CH, Hb);
    k_aggregate<true><<<ablk, 256, 0, stream>>>(off, cnt, packed, dinv, b2, Hb, Bb);
    // layer 3: Bb -> Ha -> Bb (no relu)
    k_gemm_bf16<<<GBLK, 256, 0, stream>>>(Bb, WH + 2 * CH * CH, WL + 2 * CH * CH, Ha);
    k_aggregate<false><<<ablk, 256, 0, stream>>>(off, cnt, packed, dinv, b3, Ha, Bb);

    // fused pool + linear
    k_pool_linear<<<NG, 384, 0, stream>>>(goff, Bb, Wlin, out);
}

// Round 15
// 298.857 us; speedup vs baseline: 1.0945x; 1.0376x over previous
//
#include <hip/hip_runtime.h>

#define NN 100000   // nodes
#define NE 800000   // edges  (NE % 256 == 0)
#define NG 256      // graphs
#define CH 96       // in/hidden channels
#define OC 16       // out channels
#define NBLK 391    // ceil(NN/256)
#define TM 128      // gemm node tile (8 row-tiles of 16)
#define GBLK 782    // ceil(NN/TM)

typedef __attribute__((ext_vector_type(8))) short bf16x8;
typedef __attribute__((ext_vector_type(4))) float f32x4;

// ---------------- bf16 helpers ----------------
__device__ __forceinline__ unsigned short f2bf(float x) {
    unsigned u = __float_as_uint(x);
    return (unsigned short)((u + 0x7fffu + ((u >> 16) & 1u)) >> 16);  // RNE
}
__device__ __forceinline__ float bf2f(unsigned short h) {
    return __uint_as_float(((unsigned)h) << 16);
}
__device__ __forceinline__ void split8(const float4 a, const float4 b,
                                       bf16x8& hi, bf16x8& lo) {
    float v[8] = {a.x, a.y, a.z, a.w, b.x, b.y, b.z, b.w};
#pragma unroll
    for (int j = 0; j < 8; j++) {
        unsigned short h = f2bf(v[j]);
        hi[j] = (short)h;
        lo[j] = (short)f2bf(v[j] - bf2f(h));
    }
}
__device__ __forceinline__ float4 us4_to_f4(ushort4 u) {
    return make_float4(bf2f(u.x), bf2f(u.y), bf2f(u.z), bf2f(u.w));
}
// 4 packed bf16 pairs (uint4) -> 8 floats
__device__ __forceinline__ void unpack8(uint4 v, float* f) {
    f[0] = __uint_as_float(v.x << 16); f[1] = __uint_as_float(v.x & 0xffff0000u);
    f[2] = __uint_as_float(v.y << 16); f[3] = __uint_as_float(v.y & 0xffff0000u);
    f[4] = __uint_as_float(v.z << 16); f[5] = __uint_as_float(v.z & 0xffff0000u);
    f[6] = __uint_as_float(v.w << 16); f[7] = __uint_as_float(v.w & 0xffff0000u);
}

// ---------------- init: zero cnt/gtot + prep all 3 W -> transposed bf16 hi/lo ----
__global__ __launch_bounds__(256) void k_init(int* __restrict__ cnt,
                                              const float* __restrict__ W1,
                                              const float* __restrict__ W2,
                                              const float* __restrict__ W3,
                                              unsigned short* __restrict__ WH,
                                              unsigned short* __restrict__ WL) {
    int id = blockIdx.x * 256 + threadIdx.x;
    if (id < NN + 4) cnt[id] = 0;  // cnt + gtot slot
    if (id < 3 * CH * CH) {
        int w = id / (CH * CH);
        int r = id - w * (CH * CH);
        int k = r / CH;
        int n = r - k * CH;
        const float* Ws = (w == 0) ? W1 : (w == 1) ? W2 : W3;
        float v = Ws[k * CH + n];
        unsigned short h = f2bf(v);
        WH[w * CH * CH + n * CH + k] = h;
        WL[w * CH * CH + n * CH + k] = f2bf(v - bf2f(h));
    }
}

// ---------------- front: gemm-1 (blocks < GBLK) + edge histogram (rest) --------
__global__ __launch_bounds__(256) void k_front(const float* __restrict__ X,
                                               const unsigned short* __restrict__ WH,
                                               const unsigned short* __restrict__ WL,
                                               unsigned short* __restrict__ H,
                                               const int* __restrict__ dst,
                                               int* __restrict__ cnt,
                                               int* __restrict__ slot) {
    __shared__ __align__(16) unsigned short WsH[CH * CH];  // 18 KB
    __shared__ __align__(16) unsigned short WsL[CH * CH];  // 18 KB

    const int tid = threadIdx.x;

    if (blockIdx.x >= GBLK) {  // ---- histogram path ----
        int e = (blockIdx.x - GBLK) * 256 + tid;
        slot[e] = atomicAdd(&cnt[dst[e]], 1);
        return;
    }

    // ---- gemm-1 path: H = X(fp32) @ W1, split-bf16 (3 MFMAs) ----
    const int n0 = blockIdx.x * TM;
    {
        const uint4* sH = reinterpret_cast<const uint4*>(WH);
        const uint4* sL = reinterpret_cast<const uint4*>(WL);
        uint4* dH = reinterpret_cast<uint4*>(WsH);
        uint4* dL = reinterpret_cast<uint4*>(WsL);
        for (int i = tid; i < CH * CH / 8; i += 256) {
            dH[i] = sH[i];
            dL[i] = sL[i];
        }
    }
    __syncthreads();

    const int lane = tid & 63;
    const int wave = tid >> 6;
    const int lrow = lane & 15;
    const int quad = lane >> 4;

    const float4* X4 = reinterpret_cast<const float4*>(X);

    f32x4 acc[2][6];
#pragma unroll
    for (int rt = 0; rt < 2; rt++)
#pragma unroll
        for (int ct = 0; ct < 6; ct++) acc[rt][ct] = (f32x4){0.f, 0.f, 0.f, 0.f};

    int arow[2];
#pragma unroll
    for (int rt = 0; rt < 2; rt++)
        arow[rt] = min(n0 + (wave * 2 + rt) * 16 + lrow, NN - 1);

#pragma unroll
    for (int kc = 0; kc < 3; kc++) {
        bf16x8 ahi[2], alo[2];
#pragma unroll
        for (int rt = 0; rt < 2; rt++) {
            int fo = (arow[rt] * CH + kc * 32 + quad * 8) >> 2;
            split8(X4[fo], X4[fo + 1], ahi[rt], alo[rt]);
        }
#pragma unroll
        for (int ct = 0; ct < 6; ct++) {
            int bo = (ct * 16 + lrow) * CH + kc * 32 + quad * 8;
            bf16x8 bhi = *reinterpret_cast<const bf16x8*>(&WsH[bo]);
            bf16x8 blo = *reinterpret_cast<const bf16x8*>(&WsL[bo]);
#pragma unroll
            for (int rt = 0; rt < 2; rt++) {
                acc[rt][ct] = __builtin_amdgcn_mfma_f32_16x16x32_bf16(
                    alo[rt], bhi, acc[rt][ct], 0, 0, 0);
                acc[rt][ct] = __builtin_amdgcn_mfma_f32_16x16x32_bf16(
                    ahi[rt], blo, acc[rt][ct], 0, 0, 0);
                acc[rt][ct] = __builtin_amdgcn_mfma_f32_16x16x32_bf16(
                    ahi[rt], bhi, acc[rt][ct], 0, 0, 0);
            }
        }
    }

#pragma unroll
    for (int rt = 0; rt < 2; rt++) {
        int rbase = n0 + (wave * 2 + rt) * 16 + quad * 4;
#pragma unroll
        for (int ct = 0; ct < 6; ct++) {
            int col = ct * 16 + lrow;
#pragma unroll
            for (int r = 0; r < 4; r++) {
                int row = rbase + r;
                if (row < NN) H[(size_t)row * CH + col] = f2bf(acc[rt][ct][r]);
            }
        }
    }
}

// unordered CSR offsets: wave-scan + ONE atomic per wave (G12) + dinv + goff
__global__ __launch_bounds__(256) void k_offsets(const int* __restrict__ cnt,
                                                 int* __restrict__ gtot,
                                                 int* __restrict__ off,
                                                 float* __restrict__ dinv,
                                                 const int* __restrict__ batch,
                                                 int* __restrict__ goff) {
    int i = blockIdx.x * 256 + threadIdx.x;
    int lane = threadIdx.x & 63;
    int c = (i < NN) ? cnt[i] : 0;

    // 64-lane inclusive scan
    int incl = c;
#pragma unroll
    for (int d = 1; d < 64; d <<= 1) {
        int t = __shfl_up(incl, d);
        if (lane >= d) incl += t;
    }
    int total = __shfl(incl, 63);
    int base = 0;
    if (lane == 63) base = atomicAdd(gtot, total);
    base = __shfl(base, 63);

    if (i >= NN) return;
    off[i] = base + incl - c;
    dinv[i] = rsqrtf((float)c + 1.0f);
    int b = batch[i];
    int bp = (i > 0) ? batch[i - 1] : -1;
    for (int g = bp + 1; g <= b; g++) goff[g] = i;
    if (i == NN - 1)
        for (int g = b + 1; g <= NG; g++) goff[g] = NN;
}

__global__ __launch_bounds__(256) void k_build(const int* __restrict__ src,
                                               const int* __restrict__ dst,
                                               const int* __restrict__ off,
                                               const int* __restrict__ slot,
                                               const float* __restrict__ dinv,
                                               float2* __restrict__ packed) {
    int e = blockIdx.x * 256 + threadIdx.x;
    int s = src[e];
    int d = dst[e];
    packed[off[d] + slot[e]] = make_float2(__int_as_float(s), dinv[s] * dinv[d]);
}

// ---------------- MFMA GEMM (layers 2,3): H(bf16) = X(bf16) @ W, LDS-staged W ---
__global__ __launch_bounds__(256) void k_gemm_bf16(const unsigned short* __restrict__ X,
                                                   const unsigned short* __restrict__ WH,
                                                   const unsigned short* __restrict__ WL,
                                                   unsigned short* __restrict__ H) {
    __shared__ __align__(16) unsigned short WsH[CH * CH];
    __shared__ __align__(16) unsigned short WsL[CH * CH];

    const int tid = threadIdx.x;
    const int n0 = blockIdx.x * TM;

    {
        const uint4* sH = reinterpret_cast<const uint4*>(WH);
        const uint4* sL = reinterpret_cast<const uint4*>(WL);
        uint4* dH = reinterpret_cast<uint4*>(WsH);
        uint4* dL = reinterpret_cast<uint4*>(WsL);
        for (int i = tid; i < CH * CH / 8; i += 256) {
            dH[i] = sH[i];
            dL[i] = sL[i];
        }
    }
    __syncthreads();

    const int lane = tid & 63;
    const int wave = tid >> 6;
    const int lrow = lane & 15;
    const int quad = lane >> 4;

    f32x4 acc[2][6];
#pragma unroll
    for (int rt = 0; rt < 2; rt++)
#pragma unroll
        for (int ct = 0; ct < 6; ct++) acc[rt][ct] = (f32x4){0.f, 0.f, 0.f, 0.f};

    int arow[2];
#pragma unroll
    for (int rt = 0; rt < 2; rt++)
        arow[rt] = min(n0 + (wave * 2 + rt) * 16 + lrow, NN - 1);

#pragma unroll
    for (int kc = 0; kc < 3; kc++) {
        bf16x8 ahi[2];
#pragma unroll
        for (int rt = 0; rt < 2; rt++)
            ahi[rt] = *reinterpret_cast<const bf16x8*>(
                &X[(size_t)arow[rt] * CH + kc * 32 + quad * 8]);
#pragma unroll
        for (int ct = 0; ct < 6; ct++) {
            int bo = (ct * 16 + lrow) * CH + kc * 32 + quad * 8;
            bf16x8 bhi = *reinterpret_cast<const bf16x8*>(&WsH[bo]);
            bf16x8 blo = *reinterpret_cast<const bf16x8*>(&WsL[bo]);
#pragma unroll
            for (int rt = 0; rt < 2; rt++) {
                acc[rt][ct] = __builtin_amdgcn_mfma_f32_16x16x32_bf16(
                    ahi[rt], blo, acc[rt][ct], 0, 0, 0);
                acc[rt][ct] = __builtin_amdgcn_mfma_f32_16x16x32_bf16(
                    ahi[rt], bhi, acc[rt][ct], 0, 0, 0);
            }
        }
    }

#pragma unroll
    for (int rt = 0; rt < 2; rt++) {
        int rbase = n0 + (wave * 2 + rt) * 16 + quad * 4;
#pragma unroll
        for (int ct = 0; ct < 6; ct++) {
            int col = ct * 16 + lrow;
#pragma unroll
            for (int r = 0; r < 4; r++) {
                int row = rbase + r;
                if (row < NN) H[(size_t)row * CH + col] = f2bf(acc[rt][ct][r]);
            }
        }
    }
}

// ---------------- per-dst aggregation: 12 threads/node, 4-deep 16 B gathers ------
// (R11-proven depth; 6/8-deep measured neutral -> MSHR-bound, R12/R14)
template <bool RELU>
__global__ __launch_bounds__(256) void k_aggregate(const int* __restrict__ off,
                                                   const int* __restrict__ cnt,
                                                   const float2* __restrict__ packed,
                                                   const float* __restrict__ dinv,
                                                   const float* __restrict__ bias,
                                                   const unsigned short* __restrict__ H,
                                                   unsigned short* __restrict__ Bout) {
    int idx = blockIdx.x * 256 + threadIdx.x;  // NN*12
    if (idx >= NN * 12) return;
    int n = idx / 12;
    int c8 = idx - n * 12;  // 8 channels per thread
    int e0 = off[n];
    int e1 = e0 + cnt[n];

    const uint4* H8 = reinterpret_cast<const uint4*>(H);

    float a[8];
    {
        float hf[8];
        unpack8(H8[(size_t)n * 12 + c8], hf);
        float di = dinv[n];
        float d2 = di * di;
        const float4* bias4 = reinterpret_cast<const float4*>(bias);
        float4 b0 = bias4[c8 * 2], b1 = bias4[c8 * 2 + 1];
        float bf[8] = {b0.x, b0.y, b0.z, b0.w, b1.x, b1.y, b1.z, b1.w};
#pragma unroll
        for (int j = 0; j < 8; j++) a[j] = hf[j] * d2 + bf[j];
    }

    int e = e0;
    for (; e + 4 <= e1; e += 4) {  // 4 outstanding 16B gathers
        float2 p0 = packed[e + 0];
        float2 p1 = packed[e + 1];
        float2 p2 = packed[e + 2];
        float2 p3 = packed[e + 3];
        uint4 v0 = H8[(size_t)__float_as_int(p0.x) * 12 + c8];
        uint4 v1 = H8[(size_t)__float_as_int(p1.x) * 12 + c8];
        uint4 v2 = H8[(size_t)__float_as_int(p2.x) * 12 + c8];
        uint4 v3 = H8[(size_t)__float_as_int(p3.x) * 12 + c8];
        float f0[8], f1[8], f2[8], f3[8];
        unpack8(v0, f0); unpack8(v1, f1); unpack8(v2, f2); unpack8(v3, f3);
#pragma unroll
        for (int j = 0; j < 8; j++)
            a[j] += f0[j] * p0.y + f1[j] * p1.y + f2[j] * p2.y + f3[j] * p3.y;
    }
    for (; e < e1; e++) {
        float2 pc = packed[e];
        uint4 v = H8[(size_t)__float_as_int(pc.x) * 12 + c8];
        float f[8];
        unpack8(v, f);
#pragma unroll
        for (int j = 0; j < 8; j++) a[j] += f[j] * pc.y;
    }
    if (RELU) {
#pragma unroll
        for (int j = 0; j < 8; j++) a[j] = fmaxf(a[j], 0.0f);
    }
    uint4 o;
    o.x = (unsigned)f2bf(a[0]) | ((unsigned)f2bf(a[1]) << 16);
    o.y = (unsigned)f2bf(a[2]) | ((unsigned)f2bf(a[3]) << 16);
    o.z = (unsigned)f2bf(a[4]) | ((unsigned)f2bf(a[5]) << 16);
    o.w = (unsigned)f2bf(a[6]) | ((unsigned)f2bf(a[7]) << 16);
    reinterpret_cast<uint4*>(Bout)[(size_t)n * 12 + c8] = o;
}

// ---------------- fused pool + final linear (bf16 input) ----------------
__global__ __launch_bounds__(384) void k_pool_linear(const int* __restrict__ goff,
                                                     const unsigned short* __restrict__ B,
                                                     const float* __restrict__ Wlin,
                                                     float* __restrict__ out) {
    __shared__ float4 sh[16][24];
    __shared__ float pooled[CH];
    int g = blockIdx.x;
    int t = threadIdx.x;
    int nl = t / 24;
    int c4 = t - nl * 24;
    int s = goff[g];
    int e = goff[g + 1];

    float4 acc = make_float4(0.f, 0.f, 0.f, 0.f);
    const ushort4* B4 = reinterpret_cast<const ushort4*>(B);
    for (int n = s + nl; n < e; n += 16) {
        float4 v = us4_to_f4(B4[(size_t)n * 24 + c4]);
        acc.x += v.x; acc.y += v.y; acc.z += v.z; acc.w += v.w;
    }
    sh[nl][c4] = acc;
    __syncthreads();

    if (t < 24) {
        float4 r = make_float4(0.f, 0.f, 0.f, 0.f);
#pragma unroll
        for (int j = 0; j < 16; j++) {
            float4 v = sh[j][t];
            r.x += v.x; r.y += v.y; r.z += v.z; r.w += v.w;
        }
        float inv = 1.0f / fmaxf((float)(e - s), 1.0f);
        pooled[t * 4 + 0] = r.x * inv;
        pooled[t * 4 + 1] = r.y * inv;
        pooled[t * 4 + 2] = r.z * inv;
        pooled[t * 4 + 3] = r.w * inv;
    }
    __syncthreads();

    if (t < OC) {
        float a = 0.0f;
#pragma unroll 8
        for (int k = 0; k < CH; k++) a += pooled[k] * Wlin[k * OC + t];
        out[g * OC + t] = a;
    }
}

// ---------------- launch ----------------
extern "C" void kernel_launch(void* const* d_in, const int* in_sizes, int n_in,
                              void* d_out, int out_size, void* d_ws, size_t ws_size,
                              hipStream_t stream) {
    const float* x = (const float*)d_in[0];
    const int* ei = (const int*)d_in[1];
    const int* src = ei;
    const int* dst = ei + NE;
    const int* batch = (const int*)d_in[2];
    const float* W1 = (const float*)d_in[3];
    const float* b1 = (const float*)d_in[4];
    const float* W2 = (const float*)d_in[5];
    const float* b2 = (const float*)d_in[6];
    const float* W3 = (const float*)d_in[7];
    const float* b3 = (const float*)d_in[8];
    const float* Wlin = (const float*)d_in[9];
    float* out = (float*)d_out;

    char* ws = (char*)d_ws;
    unsigned short* Ha = (unsigned short*)ws;  ws += (size_t)NN * CH * 2;  // 19.2 MB
    unsigned short* Hb = (unsigned short*)ws;  ws += (size_t)NN * CH * 2;  // 19.2 MB
    unsigned short* Bb = (unsigned short*)ws;  ws += (size_t)NN * CH * 2;  // 19.2 MB
    float2* packed = (float2*)ws;   ws += (size_t)NE * 8;        // 6.4 MB
    unsigned short* WH = (unsigned short*)ws;  ws += 3 * CH * CH * 2;  // 55 KB
    unsigned short* WL = (unsigned short*)ws;  ws += 3 * CH * CH * 2;
    float* dinv = (float*)ws;       ws += NN * 4;
    int* off = (int*)ws;            ws += NN * 4;
    int* goff = (int*)ws;           ws += 272 * 4;       // NG+1, padded
    int* cnt = (int*)ws;            ws += (NN + 4) * 4;  // +gtot slot
    int* gtot = cnt + NN;
    int* slot = (int*)Bb;  // Bb dead until agg1 writes it; slot last read by k_build

    // init (zero cnt/gtot + W prep), front (gemm1 || hist), offsets, build
    k_init<<<NBLK, 256, 0, stream>>>(cnt, W1, W2, W3, WH, WL);
    k_front<<<GBLK + NE / 256, 256, 0, stream>>>(x, WH, WL, Ha, dst, cnt, slot);
    k_offsets<<<NBLK, 256, 0, stream>>>(cnt, gtot, off, dinv, batch, goff);
    k_build<<<NE / 256, 256, 0, stream>>>(src, dst, off, slot, dinv, packed);

    const int ablk = (NN * 12 + 255) / 256;

    // layer 1 aggregate: Ha -> Bb (relu)
    k_aggregate<true><<<ablk, 256, 0, stream>>>(off, cnt, packed, dinv, b1, Ha, Bb);
    // layer 2: Bb -> Hb -> Bb (relu)
    k_gemm_bf16<<<GBLK, 256, 0, stream>>>(Bb, WH + CH * CH, WL + CH * CH, Hb);
    k_aggregate<true><<<ablk, 256, 0, stream>>>(off, cnt, packed, dinv, b2, Hb, Bb);
    // layer 3: Bb -> Ha -> Bb (no relu)
    k_gemm_bf16<<<GBLK, 256, 0, stream>>>(Bb, WH + 2 * CH * CH, WL + 2 * CH * CH, Ha);
    k_aggregate<false><<<ablk, 256, 0, stream>>>(off, cnt, packed, dinv, b3, Ha, Bb);

    // fused pool + linear
    k_pool_linear<<<NG, 384, 0, stream>>>(goff, Bb, Wlin, out);
}